// Round 1
// baseline (539.200 us; speedup 1.0000x reference)
//
#include <hip/hip_runtime.h>
#include <hip/hip_bf16.h>

// Problem constants (B=4, L=2048, D=512, M=1200, H=6)
// KEY INSIGHT: keyval is broadcast over L -> K rows identical -> softmax == 1/L exactly,
// mha == V[b] (per-batch constant), and leaky(slope=1) is identity so W2a@W2b folds.
// R9: 4-dispatch chain (was memset+5). No atomics, no memset:
//   k1: A1 cast, W2b transpose, V direct-GEMV, fill F1
//   k3: Wfold = A1@W2bT non-split-K MFMA -> bf16 WfT (transposed epilogue) + fp32 folded
//       bias row (bfold+b2b); oc = V@Wff+bff direct; fill F3
//   k4: ln1 -> X bf16; fill F4
//   k56: fused out2 GEMM (16 rows x 512 cols per block, fp32 acc) + ln2 + kv -> out3.
//        out2 never hits memory. fill F56

typedef __bf16 bf16x8 __attribute__((ext_vector_type(8)));
typedef float f32x4 __attribute__((ext_vector_type(4)));

constexpr size_t OUT3_N = 4ull * 2048 * 512;            // 4,194,304
constexpr size_t SM_N4  = (4ull * 6 * 2048 * 2048) / 4; // 25,165,824 f32x4
constexpr float  SMV    = 1.0f / 2048.0f;

// fill slice schedule (f32x4 units) — disjoint, covers SM exactly
constexpr size_t S1  = 0,        C1  = 7000000;
constexpr size_t S3  = 7000000,  C3  = 6900000;
constexpr size_t S4  = 13900000, C4  = 6500000;
constexpr size_t S56 = 20400000, C56 = 4765824;
static_assert(S56 + C56 == SM_N4, "fill slices must cover sm");

__device__ __forceinline__ void fill_slice(f32x4* __restrict__ p, size_t base, size_t cnt,
                                           int fb, int nfb){
    const f32x4 v = { SMV, SMV, SMV, SMV };
    const size_t stride = (size_t)nfb * 256;
    for (size_t j = (size_t)fb * 256 + threadIdx.x; j < cnt; j += stride)
        __builtin_nontemporal_store(v, p + base + j);
}

// ---------------- Wfold GEMM tile: 64x64 at (bm,bn), full K=2048, no split-K.
// Epilogue: rows<512 -> bf16 WfT[col][row] (transposed); row==512 -> fp32 fb[col]=acc+b2b[col]
__device__ void gemm_wf(const __bf16* __restrict__ A, const __bf16* __restrict__ BT,
                        __bf16* __restrict__ WfT, float* __restrict__ fb,
                        const float* __restrict__ b2b, int bm, int bn){
    __shared__ __bf16 As[64 * 64];
    __shared__ __bf16 Bs[64 * 64];
    const int tid = threadIdx.x, wave = tid >> 6, lane = tid & 63;
    const int r_st = wave * 8 + (lane >> 3);
    const int c8g  = (lane & 7) ^ (r_st & 7);
    const __bf16* Ag = A  + (size_t)(bm + r_st) * 2048 + c8g * 8;
    const __bf16* Bg = BT + (size_t)(bn + r_st) * 2048 + c8g * 8;
    const size_t rowskip = (size_t)32 * 2048;
    const int wm = (wave >> 1) * 32, wn = (wave & 1) * 32;
    const int lm = lane & 15, lq = lane >> 4;
    f32x4 acc[2][2] = {};
    for (int k0 = 0; k0 < 2048; k0 += 64){
        __builtin_amdgcn_global_load_lds(
            (const __attribute__((address_space(1))) void*)(Ag + k0),
            (__attribute__((address_space(3))) void*)&As[wave * 512], 16, 0, 0);
        __builtin_amdgcn_global_load_lds(
            (const __attribute__((address_space(1))) void*)(Ag + k0 + rowskip),
            (__attribute__((address_space(3))) void*)&As[2048 + wave * 512], 16, 0, 0);
        __builtin_amdgcn_global_load_lds(
            (const __attribute__((address_space(1))) void*)(Bg + k0),
            (__attribute__((address_space(3))) void*)&Bs[wave * 512], 16, 0, 0);
        __builtin_amdgcn_global_load_lds(
            (const __attribute__((address_space(1))) void*)(Bg + k0 + rowskip),
            (__attribute__((address_space(3))) void*)&Bs[2048 + wave * 512], 16, 0, 0);
        __syncthreads();
        #pragma unroll
        for (int kb = 0; kb < 64; kb += 32){
            const int sw = (((kb >> 3) + lq) ^ (lm & 7)) << 3;
            bf16x8 a0 = *(const bf16x8*)&As[(wm + lm) * 64 + sw];
            bf16x8 a1 = *(const bf16x8*)&As[(wm + 16 + lm) * 64 + sw];
            bf16x8 b0 = *(const bf16x8*)&Bs[(wn + lm) * 64 + sw];
            bf16x8 b1 = *(const bf16x8*)&Bs[(wn + 16 + lm) * 64 + sw];
            acc[0][0] = __builtin_amdgcn_mfma_f32_16x16x32_bf16(a0, b0, acc[0][0], 0, 0, 0);
            acc[0][1] = __builtin_amdgcn_mfma_f32_16x16x32_bf16(a0, b1, acc[0][1], 0, 0, 0);
            acc[1][0] = __builtin_amdgcn_mfma_f32_16x16x32_bf16(a1, b0, acc[1][0], 0, 0, 0);
            acc[1][1] = __builtin_amdgcn_mfma_f32_16x16x32_bf16(a1, b1, acc[1][1], 0, 0, 0);
        }
        __syncthreads();
    }
    #pragma unroll
    for (int mi = 0; mi < 2; ++mi)
      #pragma unroll
      for (int ni = 0; ni < 2; ++ni)
        #pragma unroll
        for (int r = 0; r < 4; ++r){
            int row = bm + wm + mi * 16 + lq * 4 + r;   // C/D: row=(lane>>4)*4+reg
            int col = bn + wn + ni * 16 + lm;           //      col=lane&15
            if (row < 512)       WfT[(size_t)col * 512 + row] = (__bf16)acc[mi][ni][r];
            else if (row == 512) fb[col] = acc[mi][ni][r] + b2b[col];
        }
}

// ---------------- k1: A1 cast, W2b transpose, V direct-GEMV; fill F1 ----------------
__global__ __launch_bounds__(256) void k1_prep(const float* __restrict__ W2a,
        const float* __restrict__ b2a, __bf16* __restrict__ A1,
        const float* __restrict__ W2b, __bf16* __restrict__ W2bT,
        const float* __restrict__ keyval, const float* __restrict__ Wkv,
        const float* __restrict__ bkv, float* __restrict__ V, f32x4* __restrict__ smf){
    __shared__ float sh[32 * 33];
    const int bid = blockIdx.x, tid = threadIdx.x;
    if (bid < 1152){
        int r = bid >> 1;
        int c = (bid & 1) * 1024 + tid * 4;
        float4 v;
        if (r < 512)       v = *(const float4*)(W2a + (size_t)r * 2048 + c);
        else if (r == 512) v = *(const float4*)(b2a + c);
        else               v = make_float4(0.f, 0.f, 0.f, 0.f);
        __bf16* o = A1 + (size_t)r * 2048 + c;
        o[0] = (__bf16)v.x; o[1] = (__bf16)v.y; o[2] = (__bf16)v.z; o[3] = (__bf16)v.w;
    } else if (bid < 2176){
        int t = bid - 1152;                    // 1024 tiles over W2b [2048][512]
        int c0 = (t & 15) * 32, r0 = (t >> 4) * 32;
        int tx = tid & 31, ty = tid >> 5;
        for (int i = ty; i < 32; i += 8)
            sh[i * 33 + tx] = W2b[(size_t)(r0 + i) * 512 + c0 + tx];
        __syncthreads();
        for (int i = ty; i < 32; i += 8)
            W2bT[(size_t)(c0 + i) * 2048 + r0 + tx] = (__bf16)sh[tx * 33 + i];
    } else if (bid < 2196){
        int i = bid - 2176;                    // 20: b(4) x mc(5), no atomics
        int b = i & 3, mc = i >> 2;
        int m = mc * 240 + tid;
        if (tid < 240){
            float acc = bkv[1200 + m];
            const float* kvb = keyval + (size_t)b * 512;
            #pragma unroll 8
            for (int d = 0; d < 512; ++d)
                acc += kvb[d] * Wkv[(size_t)d * 2400 + 1200 + m];
            V[b * 1200 + m] = acc;
        }
    }
    fill_slice(smf, S1, C1, bid, 2848);
}

// ---------------- k3: Wfold GEMM -> WfT bf16 + fb; oc direct-GEMV; fill F3 ----------------
__global__ __launch_bounds__(256) void k3_wf_oc(const __bf16* __restrict__ A1,
        const __bf16* __restrict__ W2bT, __bf16* __restrict__ WfT,
        float* __restrict__ fb, const float* __restrict__ b2b,
        const float* __restrict__ V, const float* __restrict__ Wff,
        const float* __restrict__ bff, float* __restrict__ oc, f32x4* __restrict__ smf){
    const int bid = blockIdx.x, t = threadIdx.x;
    if (bid < 72){                             // 9 row-tiles x 8 col-tiles, K=2048 full
        gemm_wf(A1, W2bT, WfT, fb, b2b, (bid % 9) * 64, (bid / 9) * 64);
    } else if (bid < 104){                     // oc: b(4) x jc(8), 4-wave K-split in-block
        __shared__ float sh[4 * 64];
        int i = bid - 72;
        int b = i & 3, jc = i >> 2;
        int wv = t >> 6, j = jc * 64 + (t & 63);
        const float* vb = V + b * 1200;
        float acc = 0.f;
        int m0 = wv * 300;
        #pragma unroll 4
        for (int m = m0; m < m0 + 300; ++m)
            acc += vb[m] * Wff[(size_t)m * 512 + j];
        sh[t] = acc;
        __syncthreads();
        if (t < 64)
            oc[b * 512 + jc * 64 + t] = sh[t] + sh[64 + t] + sh[128 + t] + sh[192 + t]
                                      + bff[jc * 64 + t];
    }
    fill_slice(smf, S3, C3, bid, 2048);
}

// ---------------- k4: ln1 -> X bf16; fill F4 ----------------
__global__ __launch_bounds__(256) void k4_ln1(const float* __restrict__ q,
        const float* __restrict__ oc, const float* __restrict__ g1,
        const float* __restrict__ b1, __bf16* __restrict__ Xb, f32x4* __restrict__ smf){
    __shared__ float sh[8];
    const int bid = blockIdx.x, t = threadIdx.x;
    if (bid < 8192){
        const int b = bid >> 11;
        const size_t base = (size_t)bid * 512;
        float2 qv = *(const float2*)(q + base + 2 * t);
        float2 ov = *(const float2*)(oc + (size_t)b * 512 + 2 * t);
        float v0 = qv.x + ov.x, v1 = qv.y + ov.y;
        float s = v0 + v1, ss = v0 * v0 + v1 * v1;
        for (int off = 32; off; off >>= 1){ s += __shfl_down(s, off); ss += __shfl_down(ss, off); }
        int wv = t >> 6, ln = t & 63;
        if (ln == 0){ sh[wv] = s; sh[4 + wv] = ss; }
        __syncthreads();
        if (t == 0){
            float S  = sh[0] + sh[1] + sh[2] + sh[3];
            float SS = sh[4] + sh[5] + sh[6] + sh[7];
            float m = S * (1.0f / 512.0f);
            float var = SS * (1.0f / 512.0f) - m * m;
            sh[0] = m; sh[1] = rsqrtf(var + 1e-5f);
        }
        __syncthreads();
        float m = sh[0], r = sh[1];
        float2 gv = *(const float2*)(g1 + 2 * t);
        float2 bv = *(const float2*)(b1 + 2 * t);
        union { __bf16 h[2]; unsigned u; } pk;
        pk.h[0] = (__bf16)((v0 - m) * r * gv.x + bv.x);
        pk.h[1] = (__bf16)((v1 - m) * r * gv.y + bv.y);
        *(unsigned*)(Xb + base + 2 * t) = pk.u;
    }
    fill_slice(smf, S4, C4, bid, 8704);
}

// ---------------- k56: fused out2-GEMM + ln2 + kv -> out3; fill F56 ----------------
// 512 blocks, each 16 rows x all 512 cols. acc stays fp32 in regs (out2 never stored).
__global__ __launch_bounds__(256) void k56_gemm_ln2(const __bf16* __restrict__ X,
        const __bf16* __restrict__ WfT, const float* __restrict__ fb,
        const float* __restrict__ g2, const float* __restrict__ b2,
        const float* __restrict__ keyval, float* __restrict__ out3,
        f32x4* __restrict__ smf){
    __shared__ __bf16 As[16 * 64];
    __shared__ __bf16 Bs[512 * 64];
    __shared__ float red[4 * 32];
    __shared__ float stats[32];
    const int bid = blockIdx.x, tid = threadIdx.x;
    if (bid < 512){
        const int wv = tid >> 6, lane = tid & 63;
        const int lm = lane & 15, lq = lane >> 4;
        const int r0 = bid * 16;
        const int srow = lane >> 3;            // 0..7
        const int c8 = lane & 7;
        f32x4 acc[8] = {};
        for (int k0 = 0; k0 < 512; k0 += 64){
            if (wv == 0){
                #pragma unroll
                for (int i = 0; i < 2; ++i){
                    int row = i * 8 + srow;
                    const __bf16* src = X + (size_t)(r0 + row) * 512 + k0
                                          + ((c8 ^ (row & 7)) << 3);
                    __builtin_amdgcn_global_load_lds(
                        (const __attribute__((address_space(1))) void*)src,
                        (__attribute__((address_space(3))) void*)&As[i * 512], 16, 0, 0);
                }
            }
            #pragma unroll
            for (int i = 0; i < 16; ++i){
                int nrow = wv * 128 + i * 8 + srow;
                const __bf16* src = WfT + (size_t)nrow * 512 + k0
                                        + ((c8 ^ (srow & 7)) << 3);
                __builtin_amdgcn_global_load_lds(
                    (const __attribute__((address_space(1))) void*)src,
                    (__attribute__((address_space(3))) void*)&Bs[(wv * 128 + i * 8) * 64],
                    16, 0, 0);
            }
            __syncthreads();
            #pragma unroll
            for (int kb = 0; kb < 64; kb += 32){
                const int sw = (((kb >> 3) + lq) ^ (lm & 7)) << 3;  // n&7 == lm&7 below
                bf16x8 a = *(const bf16x8*)&As[lm * 64 + sw];
                #pragma unroll
                for (int ni = 0; ni < 8; ++ni){
                    int n = wv * 128 + ni * 16 + lm;
                    bf16x8 b = *(const bf16x8*)&Bs[n * 64 + sw];
                    acc[ni] = __builtin_amdgcn_mfma_f32_16x16x32_bf16(a, b, acc[ni], 0, 0, 0);
                }
            }
            __syncthreads();
        }
        // epilogue: v = out2 + X + fb ; row-ln2 ; + kv
        const int b = bid >> 7;                // 128 blocks per batch
        float sum[4] = {}, ssum[4] = {};
        #pragma unroll
        for (int ni = 0; ni < 8; ++ni){
            int col = wv * 128 + ni * 16 + lm;
            float f = fb[col];
            #pragma unroll
            for (int jr = 0; jr < 4; ++jr){
                int row = lq * 4 + jr;
                float xv = (float)X[(size_t)(r0 + row) * 512 + col];
                float val = acc[ni][jr] + xv + f;
                acc[ni][jr] = val;
                sum[jr] += val; ssum[jr] += val * val;
            }
        }
        #pragma unroll
        for (int msk = 1; msk < 16; msk <<= 1){
            #pragma unroll
            for (int jr = 0; jr < 4; ++jr){
                sum[jr]  += __shfl_xor(sum[jr],  msk);
                ssum[jr] += __shfl_xor(ssum[jr], msk);
            }
        }
        if (lm == 0){
            #pragma unroll
            for (int jr = 0; jr < 4; ++jr){
                red[wv * 32 + (lq * 4 + jr) * 2]     = sum[jr];
                red[wv * 32 + (lq * 4 + jr) * 2 + 1] = ssum[jr];
            }
        }
        __syncthreads();
        if (tid < 16){
            float S  = red[tid * 2]     + red[32 + tid * 2]
                     + red[64 + tid * 2] + red[96 + tid * 2];
            float SS = red[tid * 2 + 1] + red[32 + tid * 2 + 1]
                     + red[64 + tid * 2 + 1] + red[96 + tid * 2 + 1];
            float m = S * (1.0f / 512.0f);
            float var = SS * (1.0f / 512.0f) - m * m;
            stats[tid * 2] = m;
            stats[tid * 2 + 1] = rsqrtf(var + 1e-5f);
        }
        __syncthreads();
        #pragma unroll
        for (int jr = 0; jr < 4; ++jr){
            int row = lq * 4 + jr;
            float m = stats[row * 2], ri = stats[row * 2 + 1];
            #pragma unroll
            for (int ni = 0; ni < 8; ++ni){
                int col = wv * 128 + ni * 16 + lm;
                float y = (acc[ni][jr] - m) * ri * g2[col] + b2[col]
                        + keyval[(size_t)b * 512 + col];
                out3[(size_t)(r0 + row) * 512 + col] = y;
            }
        }
    }
    fill_slice(smf, S56, C56, bid, 2048);
}

// ---------------- launch ----------------
extern "C" void kernel_launch(void* const* d_in, const int* in_sizes, int n_in,
                              void* d_out, int out_size, void* d_ws, size_t ws_size,
                              hipStream_t stream){
    const float* query  = (const float*)d_in[0];
    const float* keyval = (const float*)d_in[1];
    // d_in[2] Wq, d_in[3] bq: provably unused (softmax is uniform regardless of Q)
    const float* Wkv = (const float*)d_in[4];
    const float* bkv = (const float*)d_in[5];
    const float* Wff = (const float*)d_in[6];
    const float* bff = (const float*)d_in[7];
    const float* g1  = (const float*)d_in[8];
    const float* b1  = (const float*)d_in[9];
    const float* W2a = (const float*)d_in[10];
    const float* b2a = (const float*)d_in[11];
    const float* W2b = (const float*)d_in[12];
    const float* b2b = (const float*)d_in[13];
    const float* g2  = (const float*)d_in[14];
    const float* b2  = (const float*)d_in[15];

    float* out3 = (float*)d_out;
    f32x4* smf  = (f32x4*)(out3 + OUT3_N);

    // scratch (~13.4 MB): prefer d_ws; fall back to the sm region (never hit in practice)
    char* base = (ws_size >= (64ull << 20)) ? (char*)d_ws : (char*)smf;
    __bf16* t_A1   = (__bf16*)base;                     // [576][2048]
    __bf16* t_W2bT = t_A1 + 1179648;                    // [512][2048]
    __bf16* t_WfT  = t_W2bT + 1048576;                  // [512][512] (transposed Wfold, bf16)
    __bf16* t_X    = t_WfT + 262144;                    // [8192][512]
    float*  t_V    = (float*)(t_X + 4194304);           // [4][1200]
    float*  t_oc   = t_V + 4800;                        // [4][512]
    float*  t_fb   = t_oc + 2048;                       // [512] = b2a@W2b + b2b (fp32)

    k1_prep<<<2848, 256, 0, stream>>>(W2a, b2a, t_A1, W2b, t_W2bT,
                                      keyval, Wkv, bkv, t_V, smf);
    k3_wf_oc<<<2048, 256, 0, stream>>>(t_A1, t_W2bT, t_WfT, t_fb, b2b,
                                       t_V, Wff, bff, t_oc, smf);
    k4_ln1<<<8704, 256, 0, stream>>>(query, t_oc, g1, b1, t_X, smf);
    k56_gemm_ln2<<<2048, 256, 0, stream>>>(t_X, t_WfT, t_fb, g2, b2,
                                           keyval, out3, smf);
}